// Round 1
// baseline (1115.343 us; speedup 1.0000x reference)
//
#include <hip/hip_runtime.h>
#include <stdint.h>

typedef __bf16 bf16_t;
typedef bf16_t bf16x8 __attribute__((ext_vector_type(8)));
typedef float floatx4 __attribute__((ext_vector_type(4)));

__device__ __forceinline__ ushort f2bf(float f) {
  uint u = __float_as_uint(f);
  u += 0x7FFFu + ((u >> 16) & 1u);   // RNE; inputs are finite/normal
  return (ushort)(u >> 16);
}
__device__ __forceinline__ float bf2f(ushort h) {
  return __uint_as_float(((uint)h) << 16);
}

// ---------------- fp32 -> bf16 convert ----------------
__global__ __launch_bounds__(256) void cvt_f32_bf16(const float* __restrict__ in,
                                                    ushort* __restrict__ out,
                                                    long long n) {
  long long i = (((long long)blockIdx.x) * 256 + threadIdx.x) * 4;
  if (i + 3 < n) {
    float4 f = *(const float4*)(in + i);
    ushort4 o = make_ushort4(f2bf(f.x), f2bf(f.y), f2bf(f.z), f2bf(f.w));
    *(ushort4*)(out + i) = o;
  }
}

// ---------------- BT-form bf16 MFMA GEMM ----------------
// C[m,n] = sum_k A[m,k]*B[n,k]  (both operands k-contiguous, row strides = K)
#define BM 128
#define BN 128
#define BK 32
#define SK 40   // LDS row stride (+8 bf16 = +16B pad -> conflict-free-ish b128 reads)

enum { EP_BIAS = 0, EP_SCALE = 1, EP_ACC = 2, EP_FINAL = 3 };

template <int MODE, bool ACCUM>
__global__ __launch_bounds__(256, 2)
void gemm_bt(const ushort* __restrict__ A, const ushort* __restrict__ B,
             void* __restrict__ C, const float* __restrict__ aux,
             int M, int N, int K,
             long long sA, long long sB, long long sC, long long sAux,
             float scale) {
  __shared__ ushort As[BM * SK];
  __shared__ ushort Bs[BN * SK];
  const int b = blockIdx.z;
  const ushort* Ab = A + (long long)b * sA;
  const ushort* Bb = B + (long long)b * sB;
  const int m0 = blockIdx.y * BM;
  const int n0 = blockIdx.x * BN;
  const int t = threadIdx.x;
  const int lane = t & 63;
  const int w = t >> 6;
  const int wr = (w >> 1) * 64;
  const int wc = (w & 1) * 64;
  const int l15 = lane & 15;
  const int quad = lane >> 4;

  floatx4 acc[4][4];
  for (int i = 0; i < 4; i++)
    for (int j = 0; j < 4; j++)
      for (int r = 0; r < 4; r++) acc[i][j][r] = 0.f;

  // staging: 512 chunks of 8 bf16 per 128x32 tile; thread t does chunks t and t+256
  const int c0 = t, c1 = t + 256;
  const int ar0 = c0 >> 2, ak0 = (c0 & 3) * 8;
  const int ar1 = c1 >> 2, ak1 = (c1 & 3) * 8;

  for (int k0 = 0; k0 < K; k0 += BK) {
    uint4 va0 = *(const uint4*)(Ab + (long long)(m0 + ar0) * K + k0 + ak0);
    uint4 va1 = *(const uint4*)(Ab + (long long)(m0 + ar1) * K + k0 + ak1);
    uint4 vb0 = *(const uint4*)(Bb + (long long)(n0 + ar0) * K + k0 + ak0);
    uint4 vb1 = *(const uint4*)(Bb + (long long)(n0 + ar1) * K + k0 + ak1);
    __syncthreads();
    *(uint4*)(As + ar0 * SK + ak0) = va0;
    *(uint4*)(As + ar1 * SK + ak1) = va1;
    *(uint4*)(Bs + ar0 * SK + ak0) = vb0;
    *(uint4*)(Bs + ar1 * SK + ak1) = vb1;
    __syncthreads();

    bf16x8 af[4], bfr[4];
    for (int mi = 0; mi < 4; mi++)
      af[mi] = *(const bf16x8*)(As + (wr + mi * 16 + l15) * SK + quad * 8);
    for (int ni = 0; ni < 4; ni++)
      bfr[ni] = *(const bf16x8*)(Bs + (wc + ni * 16 + l15) * SK + quad * 8);
    for (int mi = 0; mi < 4; mi++)
      for (int ni = 0; ni < 4; ni++)
        acc[mi][ni] = __builtin_amdgcn_mfma_f32_16x16x32_bf16(af[mi], bfr[ni],
                                                              acc[mi][ni], 0, 0, 0);
  }

  for (int mi = 0; mi < 4; mi++) {
    for (int ni = 0; ni < 4; ni++) {
      const int gm0 = m0 + wr + mi * 16 + quad * 4;
      const int gn = n0 + wc + ni * 16 + l15;
      float bias = 0.f;
      if (MODE == EP_BIAS) bias = aux[gn];
      for (int r = 0; r < 4; r++) {
        const int gm = gm0 + r;
        const long long off = (long long)b * sC + (long long)gm * N + gn;
        float v = acc[mi][ni][r];
        if (MODE == EP_BIAS) {
          ((ushort*)C)[off] = f2bf(v + bias);
        } else if (MODE == EP_SCALE) {
          ((ushort*)C)[off] = f2bf(v * scale);
        } else if (MODE == EP_ACC) {
          if (ACCUM) v += bf2f(((ushort*)C)[off]);
          ((ushort*)C)[off] = f2bf(v);
        } else {  // EP_FINAL
          v += aux[(long long)b * sAux + (long long)gm * N + gn];
          ((float*)C)[off] = v;
        }
      }
    }
  }
}

// ---------------- row softmax over 2048 bf16, in place ----------------
__global__ __launch_bounds__(256) void softmax_rows(ushort* __restrict__ S) {
  const long long row = blockIdx.x;
  ushort* p = S + (row << 11);
  const int t = threadIdx.x;
  const int lane = t & 63;
  const int w = t >> 6;

  uint4 raw = *(const uint4*)(p + (t << 3));
  const ushort* rs = (const ushort*)&raw;
  float v[8];
  for (int i = 0; i < 8; i++) v[i] = bf2f(rs[i]);

  float mx = v[0];
  for (int i = 1; i < 8; i++) mx = fmaxf(mx, v[i]);
  for (int off = 32; off; off >>= 1) mx = fmaxf(mx, __shfl_xor(mx, off, 64));
  __shared__ float redm[4];
  __shared__ float reds[4];
  if (lane == 0) redm[w] = mx;
  __syncthreads();
  mx = fmaxf(fmaxf(redm[0], redm[1]), fmaxf(redm[2], redm[3]));

  float s = 0.f;
  for (int i = 0; i < 8; i++) {
    v[i] = __expf(v[i] - mx);
    s += v[i];
  }
  for (int off = 32; off; off >>= 1) s += __shfl_xor(s, off, 64);
  if (lane == 0) reds[w] = s;
  __syncthreads();
  s = (reds[0] + reds[1]) + (reds[2] + reds[3]);
  const float inv = 1.0f / s;

  ushort o[8];
  for (int i = 0; i < 8; i++) o[i] = f2bf(v[i] * inv);
  *(uint4*)(p + (t << 3)) = *(const uint4*)o;
}

// ---------------- per-batch bf16 transpose (rows x cols -> cols x rows) -------
__global__ __launch_bounds__(256) void transpose_bf16(const ushort* __restrict__ in,
                                                      ushort* __restrict__ out,
                                                      int rows, int cols) {
  __shared__ ushort tile[32][33];
  const long long ib = (long long)blockIdx.z * rows * cols;
  const int tx = threadIdx.x & 31;
  const int ty = threadIdx.x >> 5;  // 0..7
  const int r0 = blockIdx.y * 32;
  const int c0 = blockIdx.x * 32;
  for (int i = 0; i < 4; i++) {
    const int r = ty + i * 8;
    tile[r][tx] = in[ib + (long long)(r0 + r) * cols + c0 + tx];
  }
  __syncthreads();
  for (int i = 0; i < 4; i++) {
    const int r = ty + i * 8;
    out[ib + (long long)(c0 + r) * rows + r0 + tx] = tile[tx][r];
  }
}

// ---------------- orchestration ----------------
extern "C" void kernel_launch(void* const* d_in, const int* in_sizes, int n_in,
                              void* d_out, int out_size, void* d_ws, size_t ws_size,
                              hipStream_t stream) {
  const float* Itime = (const float*)d_in[0];
  const float* Ispace = (const float*)d_in[1];
  const float* x0 = (const float*)d_in[2];
  const float* bq = (const float*)d_in[4];
  const float* Wq = (const float*)d_in[3];
  const float* Wk = (const float*)d_in[5];
  const float* bk = (const float*)d_in[6];
  const float* Wv = (const float*)d_in[7];
  const float* bv = (const float*)d_in[8];
  float* out = (float*)d_out;

  const int B = 8, N = 2048, D = 512;
  const long long SZX = (long long)B * N * D;  // 8388608
  const long long SZW = 4LL * D * D;           // 1048576
  const long long SZS = (long long)B * N * N;  // 33554432

  ushort* p = (ushort*)d_ws;
  ushort* Tb = p;   p += SZX;   // Itime bf16
  ushort* Sb = p;   p += SZX;   // Ispace bf16
  ushort* Wqb = p;  p += SZW;
  ushort* Wkb = p;  p += SZW;
  ushort* Wvb = p;  p += SZW;
  ushort* Qb = p;   p += SZX;   // Q proj, then reused as V^T
  ushort* Kb = p;   p += SZX;
  ushort* Vb = p;   p += SZX;
  ushort* Abf = p;  p += SZX;   // FTT + FTS
  ushort* Cbf = p;  p += SZX;   // FSS + FST
  ushort* Sc = p;   p += SZS;   // scores / probs (bf16)
  // total ws use: ~190.8 MB

  const dim3 blk(256);
  auto cvtl = [&](const float* in, ushort* o, long long n) {
    cvt_f32_bf16<<<dim3((unsigned)(n / 4 / 256)), blk, 0, stream>>>(in, o, n);
  };
  cvtl(Itime, Tb, SZX);
  cvtl(Ispace, Sb, SZX);
  cvtl(Wq, Wqb, SZW);
  cvtl(Wk, Wkb, SZW);
  cvtl(Wv, Wvb, SZW);

  const float scale = 0.04419417382415922f;  // 1/sqrt(512)

  auto attn = [&](const ushort* qs, const ushort* ks, const ushort* vs, int pi,
                  ushort* dest, bool accum) {
    const dim3 gp(D / BN, (B * N) / BM, 1);
    gemm_bt<EP_BIAS, false><<<gp, blk, 0, stream>>>(
        qs, Wqb + pi * D * D, Qb, bq + pi * D, B * N, D, D, 0, 0, 0, 0, 0.f);
    gemm_bt<EP_BIAS, false><<<gp, blk, 0, stream>>>(
        ks, Wkb + pi * D * D, Kb, bk + pi * D, B * N, D, D, 0, 0, 0, 0, 0.f);
    gemm_bt<EP_BIAS, false><<<gp, blk, 0, stream>>>(
        vs, Wvb + pi * D * D, Vb, bv + pi * D, B * N, D, D, 0, 0, 0, 0, 0.f);
    // scores: S = scale * Q K^T   (per batch 2048x2048)
    const dim3 gs(N / BN, N / BM, B);
    gemm_bt<EP_SCALE, false><<<gs, blk, 0, stream>>>(
        Qb, Kb, Sc, nullptr, N, N, D,
        (long long)N * D, (long long)N * D, (long long)N * N, 0, scale);
    softmax_rows<<<dim3(B * N), blk, 0, stream>>>(Sc);
    // V^T into freed Qb: per batch 2048x512 -> 512x2048
    transpose_bf16<<<dim3(D / 32, N / 32, B), blk, 0, stream>>>(Vb, Qb, N, D);
    // O (+)= P V  : M=2048(q), N=512(d), K=2048(k)
    const dim3 gpv(D / BN, N / BM, B);
    if (accum)
      gemm_bt<EP_ACC, true><<<gpv, blk, 0, stream>>>(
          Sc, Qb, dest, nullptr, N, D, N,
          (long long)N * N, (long long)D * N, (long long)N * D, 0, 0.f);
    else
      gemm_bt<EP_ACC, false><<<gpv, blk, 0, stream>>>(
          Sc, Qb, dest, nullptr, N, D, N,
          (long long)N * N, (long long)D * N, (long long)N * D, 0, 0.f);
  };

  attn(Tb, Tb, Tb, 0, Abf, false);   // FTT
  attn(Tb, Sb, Sb, 2, Abf, true);    // + FTS
  attn(Sb, Sb, Sb, 1, Cbf, false);   // FSS
  attn(Sb, Tb, Tb, 3, Cbf, true);    // + FST

  // out = Abf . Cbf^T + x_origin   (fp32 out)
  const dim3 gf(N / BN, N / BM, B);
  gemm_bt<EP_FINAL, false><<<gf, blk, 0, stream>>>(
      Abf, Cbf, out, x0, N, N, D,
      (long long)N * D, (long long)N * D, (long long)N * N, (long long)N * N, 0.f);
}

// Round 2
// 1093.144 us; speedup vs baseline: 1.0203x; 1.0203x over previous
//
#include <hip/hip_runtime.h>
#include <stdint.h>

typedef __bf16 bf16_t;
typedef bf16_t bf16x8 __attribute__((ext_vector_type(8)));
typedef float floatx4 __attribute__((ext_vector_type(4)));

__device__ __forceinline__ ushort f2bf(float f) {
  uint u = __float_as_uint(f);
  u += 0x7FFFu + ((u >> 16) & 1u);   // RNE; inputs are finite/normal
  return (ushort)(u >> 16);
}
__device__ __forceinline__ float bf2f(ushort h) {
  return __uint_as_float(((uint)h) << 16);
}

// async 16B global->LDS (DMA, no VGPR round trip). LDS dest is
// wave-uniform base + lane*16 — pass the UNIFORM base, HW adds lane offset.
__device__ __forceinline__ void async_cp16(const ushort* g, ushort* l) {
  __builtin_amdgcn_global_load_lds(
      (const __attribute__((address_space(1))) uint32_t*)g,
      (__attribute__((address_space(3))) uint32_t*)l, 16, 0, 0);
}

// ---------------- fp32 -> bf16 convert ----------------
__global__ __launch_bounds__(256) void cvt_f32_bf16(const float* __restrict__ in,
                                                    ushort* __restrict__ out,
                                                    long long n) {
  long long i = (((long long)blockIdx.x) * 256 + threadIdx.x) * 4;
  if (i + 3 < n) {
    float4 f = *(const float4*)(in + i);
    ushort4 o = make_ushort4(f2bf(f.x), f2bf(f.y), f2bf(f.z), f2bf(f.w));
    *(ushort4*)(out + i) = o;
  }
}

// ---------------- BT-form bf16 MFMA GEMM (m97 structure) ----------------
// C[m,n] = sum_k A[m,k]*B[n,k]  (both operands k-contiguous, row strides = K)
// LDS layout: 128 rows x 32 k, unpadded (global_load_lds requires lane-linear).
// Bank-conflict fix via XOR swizzle folded into the GLOBAL chunk selection:
// chunk (row, slot) holds global k-chunk  slot ^ ((row>>1)&3).
#define BM 128
#define BN 128
#define BK 32

enum { EP_BIAS = 0, EP_SCALE = 1, EP_ACC = 2, EP_FINAL = 3 };

template <int MODE, bool ACCUM>
__global__ __launch_bounds__(256, 2)
void gemm_bt(const ushort* __restrict__ A, const ushort* __restrict__ B,
             void* __restrict__ C, const float* __restrict__ aux,
             int M, int N, int K,
             long long sA, long long sB, long long sC, long long sAux,
             float scale) {
  __shared__ ushort As[BM * BK];
  __shared__ ushort Bs[BN * BK];
  const int b = blockIdx.z;
  const ushort* Ab = A + (long long)b * sA;
  const ushort* Bb = B + (long long)b * sB;
  const int m0 = blockIdx.y * BM;
  const int n0 = blockIdx.x * BN;
  const int t = threadIdx.x;
  const int lane = t & 63;
  const int w = t >> 6;
  const int wr = (w >> 1) * 64;
  const int wc = (w & 1) * 64;
  const int l15 = lane & 15;
  const int quad = lane >> 4;

  floatx4 acc[4][4];
  for (int i = 0; i < 4; i++)
    for (int j = 0; j < 4; j++)
      for (int r = 0; r < 4; r++) acc[i][j][r] = 0.f;

  // staging: 512 chunks of 8 bf16 per 128x32 tile; wave w covers chunks
  // [w*128, w*128+128) via two lds-DMA instructions (64 lanes x 16B each).
  const int c0 = w * 128 + lane;
  const int c1 = c0 + 64;
  const int r0s = c0 >> 2, k0s = ((c0 & 3) ^ ((r0s >> 1) & 3)) * 8;
  const int r1s = c1 >> 2, k1s = ((c1 & 3) ^ ((r1s >> 1) & 3)) * 8;
  ushort* lA0 = As + (w * 128) * 8;        // uniform wave base (chunk*8 elems)
  ushort* lA1 = As + (w * 128 + 64) * 8;
  ushort* lB0 = Bs + (w * 128) * 8;
  ushort* lB1 = Bs + (w * 128 + 64) * 8;

  for (int k0 = 0; k0 < K; k0 += BK) {
    __syncthreads();  // prev iter's ds_reads done before overwrite
    async_cp16(Ab + (long long)(m0 + r0s) * K + k0 + k0s, lA0);
    async_cp16(Ab + (long long)(m0 + r1s) * K + k0 + k1s, lA1);
    async_cp16(Bb + (long long)(n0 + r0s) * K + k0 + k0s, lB0);
    async_cp16(Bb + (long long)(n0 + r1s) * K + k0 + k1s, lB1);
    __syncthreads();  // drains vmcnt -> staging visible

    bf16x8 af[4], bfr[4];
    for (int mi = 0; mi < 4; mi++) {
      const int row = wr + mi * 16 + l15;
      const int col = (quad ^ ((row >> 1) & 3)) * 8;
      af[mi] = *(const bf16x8*)(As + row * BK + col);
    }
    for (int ni = 0; ni < 4; ni++) {
      const int row = wc + ni * 16 + l15;
      const int col = (quad ^ ((row >> 1) & 3)) * 8;
      bfr[ni] = *(const bf16x8*)(Bs + row * BK + col);
    }
    for (int mi = 0; mi < 4; mi++)
      for (int ni = 0; ni < 4; ni++)
        acc[mi][ni] = __builtin_amdgcn_mfma_f32_16x16x32_bf16(af[mi], bfr[ni],
                                                              acc[mi][ni], 0, 0, 0);
  }

  for (int mi = 0; mi < 4; mi++) {
    for (int ni = 0; ni < 4; ni++) {
      const int gm0 = m0 + wr + mi * 16 + quad * 4;
      const int gn = n0 + wc + ni * 16 + l15;
      float bias = 0.f;
      if (MODE == EP_BIAS) bias = aux[gn];
      for (int r = 0; r < 4; r++) {
        const int gm = gm0 + r;
        const long long off = (long long)b * sC + (long long)gm * N + gn;
        float v = acc[mi][ni][r];
        if (MODE == EP_BIAS) {
          ((ushort*)C)[off] = f2bf(v + bias);
        } else if (MODE == EP_SCALE) {
          ((ushort*)C)[off] = f2bf(v * scale);
        } else if (MODE == EP_ACC) {
          if (ACCUM) v += bf2f(((ushort*)C)[off]);
          ((ushort*)C)[off] = f2bf(v);
        } else {  // EP_FINAL
          v += aux[(long long)b * sAux + (long long)gm * N + gn];
          ((float*)C)[off] = v;
        }
      }
    }
  }
}

// ---------------- row softmax over 2048 bf16, in place ----------------
__global__ __launch_bounds__(256) void softmax_rows(ushort* __restrict__ S) {
  const long long row = blockIdx.x;
  ushort* p = S + (row << 11);
  const int t = threadIdx.x;
  const int lane = t & 63;
  const int w = t >> 6;

  uint4 raw = *(const uint4*)(p + (t << 3));
  const ushort* rs = (const ushort*)&raw;
  float v[8];
  for (int i = 0; i < 8; i++) v[i] = bf2f(rs[i]);

  float mx = v[0];
  for (int i = 1; i < 8; i++) mx = fmaxf(mx, v[i]);
  for (int off = 32; off; off >>= 1) mx = fmaxf(mx, __shfl_xor(mx, off, 64));
  __shared__ float redm[4];
  __shared__ float reds[4];
  if (lane == 0) redm[w] = mx;
  __syncthreads();
  mx = fmaxf(fmaxf(redm[0], redm[1]), fmaxf(redm[2], redm[3]));

  float s = 0.f;
  for (int i = 0; i < 8; i++) {
    v[i] = __expf(v[i] - mx);
    s += v[i];
  }
  for (int off = 32; off; off >>= 1) s += __shfl_xor(s, off, 64);
  if (lane == 0) reds[w] = s;
  __syncthreads();
  s = (reds[0] + reds[1]) + (reds[2] + reds[3]);
  const float inv = 1.0f / s;

  ushort o[8];
  for (int i = 0; i < 8; i++) o[i] = f2bf(v[i] * inv);
  *(uint4*)(p + (t << 3)) = *(const uint4*)o;
}

// ---------------- per-batch bf16 transpose (rows x cols -> cols x rows) -------
__global__ __launch_bounds__(256) void transpose_bf16(const ushort* __restrict__ in,
                                                      ushort* __restrict__ out,
                                                      int rows, int cols) {
  __shared__ ushort tile[32][33];
  const long long ib = (long long)blockIdx.z * rows * cols;
  const int tx = threadIdx.x & 31;
  const int ty = threadIdx.x >> 5;  // 0..7
  const int r0 = blockIdx.y * 32;
  const int c0 = blockIdx.x * 32;
  for (int i = 0; i < 4; i++) {
    const int r = ty + i * 8;
    tile[r][tx] = in[ib + (long long)(r0 + r) * cols + c0 + tx];
  }
  __syncthreads();
  for (int i = 0; i < 4; i++) {
    const int r = ty + i * 8;
    out[ib + (long long)(c0 + r) * rows + r0 + tx] = tile[tx][r];
  }
}

// ---------------- orchestration ----------------
extern "C" void kernel_launch(void* const* d_in, const int* in_sizes, int n_in,
                              void* d_out, int out_size, void* d_ws, size_t ws_size,
                              hipStream_t stream) {
  const float* Itime = (const float*)d_in[0];
  const float* Ispace = (const float*)d_in[1];
  const float* x0 = (const float*)d_in[2];
  const float* Wq = (const float*)d_in[3];
  const float* bq = (const float*)d_in[4];
  const float* Wk = (const float*)d_in[5];
  const float* bk = (const float*)d_in[6];
  const float* Wv = (const float*)d_in[7];
  const float* bv = (const float*)d_in[8];
  float* out = (float*)d_out;

  const int B = 8, N = 2048, D = 512;
  const long long SZX = (long long)B * N * D;  // 8388608
  const long long SZW = 4LL * D * D;           // 1048576
  const long long SZS = (long long)B * N * N;  // 33554432

  ushort* p = (ushort*)d_ws;
  ushort* Tb = p;   p += SZX;   // Itime bf16
  ushort* Sb = p;   p += SZX;   // Ispace bf16
  ushort* Wqb = p;  p += SZW;
  ushort* Wkb = p;  p += SZW;
  ushort* Wvb = p;  p += SZW;
  ushort* Qb = p;   p += SZX;   // Q proj, then reused as V^T
  ushort* Kb = p;   p += SZX;
  ushort* Vb = p;   p += SZX;
  ushort* Abf = p;  p += SZX;   // FTT + FTS
  ushort* Cbf = p;  p += SZX;   // FSS + FST
  ushort* Sc = p;   p += SZS;   // scores / probs (bf16)
  // total ws use: ~190.8 MB

  const dim3 blk(256);
  auto cvtl = [&](const float* in, ushort* o, long long n) {
    cvt_f32_bf16<<<dim3((unsigned)(n / 4 / 256)), blk, 0, stream>>>(in, o, n);
  };
  cvtl(Itime, Tb, SZX);
  cvtl(Ispace, Sb, SZX);
  cvtl(Wq, Wqb, SZW);
  cvtl(Wk, Wkb, SZW);
  cvtl(Wv, Wvb, SZW);

  const float scale = 0.04419417382415922f;  // 1/sqrt(512)

  auto attn = [&](const ushort* qs, const ushort* ks, const ushort* vs, int pi,
                  ushort* dest, bool accum) {
    const dim3 gp(D / BN, (B * N) / BM, 1);
    gemm_bt<EP_BIAS, false><<<gp, blk, 0, stream>>>(
        qs, Wqb + pi * D * D, Qb, bq + pi * D, B * N, D, D, 0, 0, 0, 0, 0.f);
    gemm_bt<EP_BIAS, false><<<gp, blk, 0, stream>>>(
        ks, Wkb + pi * D * D, Kb, bk + pi * D, B * N, D, D, 0, 0, 0, 0, 0.f);
    gemm_bt<EP_BIAS, false><<<gp, blk, 0, stream>>>(
        vs, Wvb + pi * D * D, Vb, bv + pi * D, B * N, D, D, 0, 0, 0, 0, 0.f);
    // scores: S = scale * Q K^T   (per batch 2048x2048)
    const dim3 gs(N / BN, N / BM, B);
    gemm_bt<EP_SCALE, false><<<gs, blk, 0, stream>>>(
        Qb, Kb, Sc, nullptr, N, N, D,
        (long long)N * D, (long long)N * D, (long long)N * N, 0, scale);
    softmax_rows<<<dim3(B * N), blk, 0, stream>>>(Sc);
    // V^T into freed Qb: per batch 2048x512 -> 512x2048
    transpose_bf16<<<dim3(D / 32, N / 32, B), blk, 0, stream>>>(Vb, Qb, N, D);
    // O (+)= P V  : M=2048(q), N=512(d), K=2048(k)
    const dim3 gpv(D / BN, N / BM, B);
    if (accum)
      gemm_bt<EP_ACC, true><<<gpv, blk, 0, stream>>>(
          Sc, Qb, dest, nullptr, N, D, N,
          (long long)N * N, (long long)D * N, (long long)N * D, 0, 0.f);
    else
      gemm_bt<EP_ACC, false><<<gpv, blk, 0, stream>>>(
          Sc, Qb, dest, nullptr, N, D, N,
          (long long)N * N, (long long)D * N, (long long)N * D, 0, 0.f);
  };

  attn(Tb, Tb, Tb, 0, Abf, false);   // FTT
  attn(Tb, Sb, Sb, 2, Abf, true);    // + FTS
  attn(Sb, Sb, Sb, 1, Cbf, false);   // FSS
  attn(Sb, Tb, Tb, 3, Cbf, true);    // + FST

  // out = Abf . Cbf^T + x_origin   (fp32 out)
  const dim3 gf(N / BN, N / BM, B);
  gemm_bt<EP_FINAL, false><<<gf, blk, 0, stream>>>(
      Abf, Cbf, out, x0, N, N, D,
      (long long)N * D, (long long)N * D, (long long)N * N, (long long)N * N, 0.f);
}

// Round 3
// 959.396 us; speedup vs baseline: 1.1625x; 1.1394x over previous
//
#include <hip/hip_runtime.h>
#include <stdint.h>

typedef __bf16 bf16_t;
typedef bf16_t bf16x8 __attribute__((ext_vector_type(8)));
typedef float floatx4 __attribute__((ext_vector_type(4)));

__device__ __forceinline__ ushort f2bf(float f) {
  uint u = __float_as_uint(f);
  u += 0x7FFFu + ((u >> 16) & 1u);   // RNE; inputs finite/normal
  return (ushort)(u >> 16);
}
__device__ __forceinline__ float bf2f(ushort h) {
  return __uint_as_float(((uint)h) << 16);
}

// async 16B global->LDS DMA. LDS dest = wave-uniform base + lane*16.
__device__ __forceinline__ void async_cp16(const ushort* g, ushort* l) {
  __builtin_amdgcn_global_load_lds(
      (const __attribute__((address_space(1))) uint32_t*)g,
      (__attribute__((address_space(3))) uint32_t*)l, 16, 0, 0);
}

// ---------------- fp32 -> bf16 convert ----------------
__global__ __launch_bounds__(256) void cvt_f32_bf16(const float* __restrict__ in,
                                                    ushort* __restrict__ out,
                                                    long long n) {
  long long i = (((long long)blockIdx.x) * 256 + threadIdx.x) * 4;
  if (i + 3 < n) {
    float4 f = *(const float4*)(in + i);
    ushort4 o = make_ushort4(f2bf(f.x), f2bf(f.y), f2bf(f.z), f2bf(f.w));
    *(ushort4*)(out + i) = o;
  }
}

// ---- pack Wq/Wk/Wv (fp32) -> Wp[4][1536][512] bf16 (rows: Q,K,V stacked) ----
__global__ __launch_bounds__(256) void pack_w(const float* __restrict__ Wq,
                                              const float* __restrict__ Wk,
                                              const float* __restrict__ Wv,
                                              ushort* __restrict__ Wp) {
  long long t4 = (((long long)blockIdx.x) * 256 + threadIdx.x) * 4;  // < 4*1536*512
  const int k = (int)(t4 & 511);
  const int jr = (int)(t4 >> 9);       // 0..6143
  const int pi = jr / 1536;
  const int j = jr - pi * 1536;
  const int type = j >> 9;             // 0=Q 1=K 2=V
  const int jj = j & 511;
  const float* src = (type == 0 ? Wq : type == 1 ? Wk : Wv) +
                     ((long long)(pi * 512 + jj) << 9) + k;
  float4 f = *(const float4*)src;
  ushort4 o = make_ushort4(f2bf(f.x), f2bf(f.y), f2bf(f.z), f2bf(f.w));
  *(ushort4*)(Wp + t4) = o;
}

__global__ __launch_bounds__(256) void pack_b(const float* __restrict__ bq,
                                              const float* __restrict__ bk,
                                              const float* __restrict__ bv,
                                              float* __restrict__ Bp) {
  const int i = blockIdx.x * 256 + threadIdx.x;  // < 6144
  const int pi = i / 1536;
  const int j = i - pi * 1536;
  const int type = j >> 9;
  const int jj = j & 511;
  Bp[i] = (type == 0 ? bq : type == 1 ? bk : bv)[pi * 512 + jj];
}

// ---------------- BT-form bf16 MFMA GEMM ----------------
// C[m,n] = sum_k A[m,k]*B[n,k]; both operands k-contiguous (lda/ldb strides).
// BK=64, LDS unpadded lane-linear (global_load_lds). Bank balance via XOR
// swizzle folded into the GLOBAL chunk choice: LDS[row][c] = G[row][c^(row&7)].
#define BM 128
#define BN 128
#define BK 64

enum { EP_BIAS = 0, EP_KV = 1, EP_SCALE = 2, EP_ACC = 3, EP_FINAL = 4 };

template <int MODE, bool ACCUM>
__global__ __launch_bounds__(256, 2)
void gemm_bt(const ushort* __restrict__ A, const ushort* __restrict__ B,
             void* __restrict__ C, void* __restrict__ C2,
             const float* __restrict__ aux,
             int M, int N, int K, int lda, int ldb, int ldc,
             long long sA, long long sB, long long sC, long long sAux,
             float scale) {
  __shared__ ushort As[BM * BK];
  __shared__ ushort Bs[BN * BK];
  const int b = blockIdx.z;
  const ushort* Ab = A + (long long)b * sA;
  const ushort* Bb = B + (long long)b * sB;
  const int m0 = blockIdx.y * BM;
  const int n0 = blockIdx.x * BN;
  const int t = threadIdx.x;
  const int lane = t & 63;
  const int w = t >> 6;
  const int wr = (w >> 1) * 64;
  const int wc = (w & 1) * 64;
  const int l15 = lane & 15;
  const int quad = lane >> 4;

  floatx4 acc[4][4];
  for (int i = 0; i < 4; i++)
    for (int j = 0; j < 4; j++)
      for (int r = 0; r < 4; r++) acc[i][j][r] = 0.f;

  // staging: 1024 chunks of 8 bf16 per 128x64 tile; wave w covers chunks
  // [w*256, w*256+256) via 4 lds-DMA instructions per operand.
  long long offA[4], offB[4];
  ushort* lA[4];
  ushort* lB[4];
#pragma unroll
  for (int i = 0; i < 4; i++) {
    const int q = w * 256 + i * 64 + lane;
    const int row = q >> 3;
    const int gk = ((q & 7) ^ (row & 7)) * 8;
    offA[i] = (long long)(m0 + row) * lda + gk;
    offB[i] = (long long)(n0 + row) * ldb + gk;
    lA[i] = As + (w * 256 + i * 64) * 8;
    lB[i] = Bs + (w * 256 + i * 64) * 8;
  }

  const int x7 = l15 & 7;
  for (int k0 = 0; k0 < K; k0 += BK) {
    __syncthreads();  // prev iter's ds_reads done before overwrite
#pragma unroll
    for (int i = 0; i < 4; i++) async_cp16(Ab + offA[i] + k0, lA[i]);
#pragma unroll
    for (int i = 0; i < 4; i++) async_cp16(Bb + offB[i] + k0, lB[i]);
    __syncthreads();  // drains vmcnt -> staging visible

#pragma unroll
    for (int s = 0; s < 2; s++) {
      const int col = ((s * 4 + quad) ^ x7) * 8;
      bf16x8 af[4], bfr[4];
#pragma unroll
      for (int mi = 0; mi < 4; mi++)
        af[mi] = *(const bf16x8*)(As + (wr + mi * 16 + l15) * BK + col);
#pragma unroll
      for (int ni = 0; ni < 4; ni++)
        bfr[ni] = *(const bf16x8*)(Bs + (wc + ni * 16 + l15) * BK + col);
#pragma unroll
      for (int mi = 0; mi < 4; mi++)
#pragma unroll
        for (int ni = 0; ni < 4; ni++)
          acc[mi][ni] = __builtin_amdgcn_mfma_f32_16x16x32_bf16(
              af[mi], bfr[ni], acc[mi][ni], 0, 0, 0);
    }
  }

#pragma unroll
  for (int mi = 0; mi < 4; mi++) {
#pragma unroll
    for (int ni = 0; ni < 4; ni++) {
      const int gm0 = m0 + wr + mi * 16 + quad * 4;
      const int gn = n0 + wc + ni * 16 + l15;
      if (MODE == EP_KV) {
        const float bias = aux[gn];
        if (gn < 512) {  // K half: normal layout (wave-uniform branch)
          for (int r = 0; r < 4; r++)
            ((ushort*)C)[(long long)(gm0 + r) * ldc + gn] =
                f2bf(acc[mi][ni][r] + bias);
        } else {  // V half: write transposed Vt[b][gn-512][token]
          const int b2 = gm0 >> 11;
          const int gmL = gm0 & 2047;
          ushort4 o;
          o.x = f2bf(acc[mi][ni][0] + bias);
          o.y = f2bf(acc[mi][ni][1] + bias);
          o.z = f2bf(acc[mi][ni][2] + bias);
          o.w = f2bf(acc[mi][ni][3] + bias);
          *(ushort4*)((ushort*)C2 + (long long)b2 * (512 * 2048) +
                      (long long)(gn - 512) * 2048 + gmL) = o;
        }
      } else {
        float bias = 0.f;
        if (MODE == EP_BIAS) bias = aux[gn];
        for (int r = 0; r < 4; r++) {
          const int gm = gm0 + r;
          const long long off = (long long)b * sC + (long long)gm * ldc + gn;
          float v = acc[mi][ni][r];
          if (MODE == EP_BIAS) {
            ((ushort*)C)[off] = f2bf(v + bias);
          } else if (MODE == EP_SCALE) {
            ((ushort*)C)[off] = f2bf(v * scale);
          } else if (MODE == EP_ACC) {
            if (ACCUM) v += bf2f(((ushort*)C)[off]);
            ((ushort*)C)[off] = f2bf(v);
          } else {  // EP_FINAL
            v += aux[(long long)b * sAux + (long long)gm * N + gn];
            ((float*)C)[off] = v;
          }
        }
      }
    }
  }
}

// ---------------- row softmax over 2048 bf16, in place ----------------
__global__ __launch_bounds__(256) void softmax_rows(ushort* __restrict__ S) {
  const long long row = blockIdx.x;
  ushort* p = S + (row << 11);
  const int t = threadIdx.x;
  const int lane = t & 63;
  const int w = t >> 6;

  uint4 raw = *(const uint4*)(p + (t << 3));
  const ushort* rs = (const ushort*)&raw;
  float v[8];
  for (int i = 0; i < 8; i++) v[i] = bf2f(rs[i]);

  float mx = v[0];
  for (int i = 1; i < 8; i++) mx = fmaxf(mx, v[i]);
  for (int off = 32; off; off >>= 1) mx = fmaxf(mx, __shfl_xor(mx, off, 64));
  __shared__ float redm[4];
  __shared__ float reds[4];
  if (lane == 0) redm[w] = mx;
  __syncthreads();
  mx = fmaxf(fmaxf(redm[0], redm[1]), fmaxf(redm[2], redm[3]));

  float s = 0.f;
  for (int i = 0; i < 8; i++) {
    v[i] = __expf(v[i] - mx);
    s += v[i];
  }
  for (int off = 32; off; off >>= 1) s += __shfl_xor(s, off, 64);
  if (lane == 0) reds[w] = s;
  __syncthreads();
  s = (reds[0] + reds[1]) + (reds[2] + reds[3]);
  const float inv = 1.0f / s;

  ushort o[8];
  for (int i = 0; i < 8; i++) o[i] = f2bf(v[i] * inv);
  *(uint4*)(p + (t << 3)) = *(const uint4*)o;
}

// ---------------- orchestration ----------------
extern "C" void kernel_launch(void* const* d_in, const int* in_sizes, int n_in,
                              void* d_out, int out_size, void* d_ws, size_t ws_size,
                              hipStream_t stream) {
  const float* Itime = (const float*)d_in[0];
  const float* Ispace = (const float*)d_in[1];
  const float* x0 = (const float*)d_in[2];
  const float* Wq = (const float*)d_in[3];
  const float* bq = (const float*)d_in[4];
  const float* Wk = (const float*)d_in[5];
  const float* bk = (const float*)d_in[6];
  const float* Wv = (const float*)d_in[7];
  const float* bv = (const float*)d_in[8];
  float* out = (float*)d_out;

  const long long SZX = 8388608;        // 8*2048*512
  const long long SZWP = 4LL * 1536 * 512;
  const long long SZS = 33554432;       // 8*2048*2048

  ushort* p = (ushort*)d_ws;
  ushort* Tb = p;   p += SZX;    // Itime bf16
  ushort* Sb = p;   p += SZX;    // Ispace bf16
  ushort* Wp = p;   p += SZWP;   // packed [4][1536][512] (Q,K,V rows)
  ushort* Qb = p;   p += SZX;    // Q proj [16384][512]
  ushort* Kb = p;   p += SZX;    // K proj [16384][512]
  ushort* Vt = p;   p += SZX;    // V^T [8][512][2048]
  ushort* Abf = p;  p += SZX;    // FTT + FTS
  ushort* Cbf = p;  p += SZX;    // FSS + FST
  ushort* Sc = p;   p += SZS;    // scores / probs (bf16)
  float* Bp = (float*)p;         // packed biases [4][1536] fp32 (24 KB)
  // total ws use ≈ 190.9 MB

  const dim3 blk(256);
  cvt_f32_bf16<<<dim3(8192), blk, 0, stream>>>(Itime, Tb, SZX);
  cvt_f32_bf16<<<dim3(8192), blk, 0, stream>>>(Ispace, Sb, SZX);
  pack_w<<<dim3(3072), blk, 0, stream>>>(Wq, Wk, Wv, Wp);
  pack_b<<<dim3(24), blk, 0, stream>>>(bq, bk, bv, Bp);

  const float scale = 0.04419417382415922f;  // 1/sqrt(512)

  auto attn = [&](const ushort* qs, const ushort* kvs, int pi,
                  ushort* dest, bool accum) {
    const ushort* Wqi = Wp + (long long)pi * 1536 * 512;
    const ushort* Wkvi = Wqi + 512 * 512;
    const float* Bqi = Bp + pi * 1536;
    // Q projection: [16384,512] = qs(16384x512) . WqT
    gemm_bt<EP_BIAS, false><<<dim3(4, 128, 1), blk, 0, stream>>>(
        qs, Wqi, Qb, nullptr, Bqi, 16384, 512, 512, 512, 512, 512,
        0, 0, 0, 0, 0.f);
    // K+V fused projection: K -> Kb (normal), V -> Vt (transposed per batch)
    gemm_bt<EP_KV, false><<<dim3(8, 128, 1), blk, 0, stream>>>(
        kvs, Wkvi, Kb, Vt, Bqi + 512, 16384, 1024, 512, 512, 512, 512,
        0, 0, 0, 0, 0.f);
    // scores: S = scale * Q K^T (per batch 2048x2048)
    gemm_bt<EP_SCALE, false><<<dim3(16, 16, 8), blk, 0, stream>>>(
        Qb, Kb, Sc, nullptr, nullptr, 2048, 2048, 512, 512, 512, 2048,
        1048576, 1048576, 4194304, 0, scale);
    softmax_rows<<<dim3(16384), blk, 0, stream>>>(Sc);
    // O (+)= P V : per batch M=2048, N=512, K=2048; B operand = Vt rows
    if (accum)
      gemm_bt<EP_ACC, true><<<dim3(4, 16, 8), blk, 0, stream>>>(
          Sc, Vt, dest, nullptr, nullptr, 2048, 512, 2048, 2048, 2048, 512,
          4194304, 1048576, 1048576, 0, 0.f);
    else
      gemm_bt<EP_ACC, false><<<dim3(4, 16, 8), blk, 0, stream>>>(
          Sc, Vt, dest, nullptr, nullptr, 2048, 512, 2048, 2048, 2048, 512,
          4194304, 1048576, 1048576, 0, 0.f);
  };

  attn(Tb, Tb, 0, Abf, false);   // FTT
  attn(Tb, Sb, 2, Abf, true);    // + FTS
  attn(Sb, Sb, 1, Cbf, false);   // FSS
  attn(Sb, Tb, 3, Cbf, true);    // + FST

  // out = Abf . Cbf^T + x_origin (fp32)
  gemm_bt<EP_FINAL, false><<<dim3(16, 16, 8), blk, 0, stream>>>(
      Abf, Cbf, out, nullptr, x0, 2048, 2048, 512, 512, 512, 2048,
      1048576, 1048576, 4194304, 4194304, 0.f);
}